// Round 1
// baseline (2373.017 us; speedup 1.0000x reference)
//
#include <hip/hip_runtime.h>

#define N_NODES 100000
#define N_EDGES 1200000
#define LAYERS 4
#define SLOPE 0.01f

__device__ __forceinline__ float leaky(float v) { return v >= 0.f ? v : SLOPE * v; }

// ---------------------------------------------------------------------------
// Encoder: h = leaky(x @ W1 + b1) @ W2 + b2     [N,16] -> [N,64]
// One thread per node. W1 transposed into LDS as [128][16], W2 [128][64].
// ---------------------------------------------------------------------------
__global__ __launch_bounds__(256) void enc_kernel(
    const float* __restrict__ x,
    const float* __restrict__ W1, const float* __restrict__ b1,
    const float* __restrict__ W2, const float* __restrict__ b2,
    float* __restrict__ H)
{
    __shared__ float sW1[128 * 16];   // [k][i] = W1[i][k]
    __shared__ float sW2[128 * 64];
    __shared__ float sb1[128];
    __shared__ float sb2[64];
    for (int idx = threadIdx.x; idx < 16 * 128; idx += 256) {
        int i = idx / 128, k = idx % 128;
        sW1[k * 16 + i] = W1[idx];
    }
    for (int idx = threadIdx.x; idx < 128 * 64; idx += 256) sW2[idx] = W2[idx];
    if (threadIdx.x < 128) sb1[threadIdx.x] = b1[threadIdx.x];
    if (threadIdx.x < 64)  sb2[threadIdx.x] = b2[threadIdx.x];
    __syncthreads();

    int n = blockIdx.x * 256 + threadIdx.x;
    if (n >= N_NODES) return;

    float xi[16];
    const float4* xv = (const float4*)(x + (size_t)n * 16);
    #pragma unroll
    for (int i = 0; i < 4; i++) {
        float4 t = xv[i];
        xi[4 * i] = t.x; xi[4 * i + 1] = t.y; xi[4 * i + 2] = t.z; xi[4 * i + 3] = t.w;
    }
    float acc[64];
    #pragma unroll
    for (int j = 0; j < 64; j++) acc[j] = sb2[j];

    for (int k = 0; k < 128; k++) {
        float t = sb1[k];
        const float4* w1r = (const float4*)(sW1 + k * 16);
        #pragma unroll
        for (int i = 0; i < 4; i++) {
            float4 w = w1r[i];
            t += xi[4 * i] * w.x + xi[4 * i + 1] * w.y + xi[4 * i + 2] * w.z + xi[4 * i + 3] * w.w;
        }
        t = leaky(t);
        const float4* w2r = (const float4*)(sW2 + k * 64);
        #pragma unroll
        for (int j = 0; j < 16; j++) {
            float4 w = w2r[j];
            acc[4 * j] += t * w.x; acc[4 * j + 1] += t * w.y;
            acc[4 * j + 2] += t * w.z; acc[4 * j + 3] += t * w.w;
        }
    }
    float4* out = (float4*)(H + (size_t)n * 64);
    #pragma unroll
    for (int j = 0; j < 16; j++)
        out[j] = make_float4(acc[4 * j], acc[4 * j + 1], acc[4 * j + 2], acc[4 * j + 3]);
}

// ---------------------------------------------------------------------------
// Per-layer: hn = LN(h)*g+b (in-place into H);
//   Y = hn @ node_W + node_b + edge_b   (scatter adds msg contribution later)
//   Z = hn @ edge_W                     (so msg@edge_W == sum_e w_e * Z[src])
// ---------------------------------------------------------------------------
__global__ __launch_bounds__(256) void layer_ln_gemm(
    float* H,                              // [N,64] in: h, out: hn (in-place)
    float* __restrict__ Y,                 // [N,32]
    float* __restrict__ Z,                 // [N,32]
    const float* __restrict__ ln_g, const float* __restrict__ ln_b,
    const float* __restrict__ nodeW, const float* __restrict__ node_b,
    const float* __restrict__ edgeW, const float* __restrict__ edge_b)
{
    __shared__ float sNW[64 * 32];
    __shared__ float sEW[64 * 32];
    __shared__ float sg[64], sb[64], sby[32];
    for (int idx = threadIdx.x; idx < 64 * 32; idx += 256) {
        sNW[idx] = nodeW[idx];
        sEW[idx] = edgeW[idx];
    }
    if (threadIdx.x < 64) { sg[threadIdx.x] = ln_g[threadIdx.x]; sb[threadIdx.x] = ln_b[threadIdx.x]; }
    if (threadIdx.x < 32) { sby[threadIdx.x] = node_b[threadIdx.x] + edge_b[threadIdx.x]; }
    __syncthreads();

    int n = blockIdx.x * 256 + threadIdx.x;
    if (n >= N_NODES) return;

    const float4* hv = (const float4*)(H + (size_t)n * 64);
    float s = 0.f, s2 = 0.f;
    #pragma unroll
    for (int i = 0; i < 16; i++) {
        float4 t = hv[i];
        s  += t.x + t.y + t.z + t.w;
        s2 += t.x * t.x + t.y * t.y + t.z * t.z + t.w * t.w;
    }
    float mu  = s * (1.f / 64.f);
    float var = s2 * (1.f / 64.f) - mu * mu;
    float rs  = rsqrtf(var + 1e-5f);

    float accY[32], accZ[32];
    #pragma unroll
    for (int j = 0; j < 32; j++) { accY[j] = sby[j]; accZ[j] = 0.f; }

    float4* hnv = (float4*)(H + (size_t)n * 64);
    for (int kc = 0; kc < 16; kc++) {
        float4 hc = hv[kc];            // read chunk before overwriting it
        float hn4[4];
        #pragma unroll
        for (int u = 0; u < 4; u++) {
            int k = kc * 4 + u;
            float hval = (u == 0) ? hc.x : (u == 1) ? hc.y : (u == 2) ? hc.z : hc.w;
            float hnk = (hval - mu) * rs * sg[k] + sb[k];
            hn4[u] = hnk;
            const float4* nwr = (const float4*)(sNW + k * 32);
            const float4* ewr = (const float4*)(sEW + k * 32);
            #pragma unroll
            for (int j = 0; j < 8; j++) {
                float4 wn = nwr[j];
                float4 we = ewr[j];
                accY[4 * j]     += hnk * wn.x; accY[4 * j + 1] += hnk * wn.y;
                accY[4 * j + 2] += hnk * wn.z; accY[4 * j + 3] += hnk * wn.w;
                accZ[4 * j]     += hnk * we.x; accZ[4 * j + 1] += hnk * we.y;
                accZ[4 * j + 2] += hnk * we.z; accZ[4 * j + 3] += hnk * we.w;
            }
        }
        hnv[kc] = make_float4(hn4[0], hn4[1], hn4[2], hn4[3]);
    }
    float4* yv = (float4*)(Y + (size_t)n * 32);
    float4* zv = (float4*)(Z + (size_t)n * 32);
    #pragma unroll
    for (int j = 0; j < 8; j++) {
        yv[j] = make_float4(accY[4 * j], accY[4 * j + 1], accY[4 * j + 2], accY[4 * j + 3]);
        zv[j] = make_float4(accZ[4 * j], accZ[4 * j + 1], accZ[4 * j + 2], accZ[4 * j + 3]);
    }
}

// ---------------------------------------------------------------------------
// Scatter: Y[dst] += w_e * Z[src]   (8 lanes per edge, float4 each)
// ---------------------------------------------------------------------------
__global__ __launch_bounds__(256) void scatter_kernel(
    const int* __restrict__ src, const int* __restrict__ dst,
    const float* __restrict__ w,
    const float* __restrict__ Z, float* __restrict__ Y)
{
    int gid = blockIdx.x * 256 + threadIdx.x;
    if (gid >= N_EDGES * 8) return;
    int e = gid >> 3;
    int j = gid & 7;
    int s = src[e];
    int d = dst[e];
    float we = w[e];
    float4 zv = ((const float4*)Z)[(size_t)s * 8 + j];
    float* yp = Y + (size_t)d * 32 + j * 4;
    unsafeAtomicAdd(yp + 0, we * zv.x);
    unsafeAtomicAdd(yp + 1, we * zv.y);
    unsafeAtomicAdd(yp + 2, we * zv.z);
    unsafeAtomicAdd(yp + 3, we * zv.w);
}

// ---------------------------------------------------------------------------
// MLP + residual: h = leaky(Y) @ mlp_W + mlp_b + hn   (H holds hn, overwritten)
// ---------------------------------------------------------------------------
__global__ __launch_bounds__(256) void mlp_kernel(
    const float* __restrict__ Y, float* H,
    const float* __restrict__ mlpW, const float* __restrict__ mlp_b)
{
    __shared__ float sW[32 * 64];
    __shared__ float sb2[64];
    for (int idx = threadIdx.x; idx < 32 * 64; idx += 256) sW[idx] = mlpW[idx];
    if (threadIdx.x < 64) sb2[threadIdx.x] = mlp_b[threadIdx.x];
    __syncthreads();

    int n = blockIdx.x * 256 + threadIdx.x;
    if (n >= N_NODES) return;

    float ly[32];
    const float4* yv = (const float4*)(Y + (size_t)n * 32);
    #pragma unroll
    for (int i = 0; i < 8; i++) {
        float4 t = yv[i];
        ly[4 * i] = leaky(t.x); ly[4 * i + 1] = leaky(t.y);
        ly[4 * i + 2] = leaky(t.z); ly[4 * i + 3] = leaky(t.w);
    }
    float acc[64];
    #pragma unroll
    for (int j = 0; j < 64; j++) acc[j] = sb2[j];
    for (int k = 0; k < 32; k++) {
        float t = ly[k];
        const float4* wr = (const float4*)(sW + k * 64);
        #pragma unroll
        for (int j = 0; j < 16; j++) {
            float4 wv = wr[j];
            acc[4 * j] += t * wv.x; acc[4 * j + 1] += t * wv.y;
            acc[4 * j + 2] += t * wv.z; acc[4 * j + 3] += t * wv.w;
        }
    }
    float4* hp = (float4*)(H + (size_t)n * 64);
    #pragma unroll
    for (int j = 0; j < 16; j++) {
        float4 hn = hp[j];   // residual
        hp[j] = make_float4(acc[4 * j] + hn.x, acc[4 * j + 1] + hn.y,
                            acc[4 * j + 2] + hn.z, acc[4 * j + 3] + hn.w);
    }
}

// ---------------------------------------------------------------------------
// Decoder: out = leaky(h @ W1 + b1) @ W2 + b2     [N,64] -> [N,3]
// ---------------------------------------------------------------------------
__global__ __launch_bounds__(256) void dec_kernel(
    const float* __restrict__ H,
    const float* __restrict__ W1, const float* __restrict__ b1,
    const float* __restrict__ W2, const float* __restrict__ b2,
    float* __restrict__ out)
{
    __shared__ float sW1t[24 * 64];   // [t][k] = W1[k][t]
    __shared__ float sb1[24];
    __shared__ float sW2[24 * 3];
    __shared__ float sb2v[3];
    for (int idx = threadIdx.x; idx < 64 * 24; idx += 256) {
        int k = idx / 24, t = idx % 24;
        sW1t[t * 64 + k] = W1[idx];
    }
    if (threadIdx.x < 24) sb1[threadIdx.x] = b1[threadIdx.x];
    if (threadIdx.x < 72) sW2[threadIdx.x] = W2[threadIdx.x];
    if (threadIdx.x < 3)  sb2v[threadIdx.x] = b2[threadIdx.x];
    __syncthreads();

    int n = blockIdx.x * 256 + threadIdx.x;
    if (n >= N_NODES) return;

    float hid[24];
    #pragma unroll
    for (int t = 0; t < 24; t++) hid[t] = sb1[t];

    const float4* hv = (const float4*)(H + (size_t)n * 64);
    for (int i = 0; i < 16; i++) {
        float4 hc = hv[i];
        #pragma unroll
        for (int t = 0; t < 24; t++) {
            float4 wv = *(const float4*)(sW1t + t * 64 + 4 * i);
            hid[t] += hc.x * wv.x + hc.y * wv.y + hc.z * wv.z + hc.w * wv.w;
        }
    }
    float o0 = sb2v[0], o1 = sb2v[1], o2 = sb2v[2];
    #pragma unroll
    for (int t = 0; t < 24; t++) {
        float lt = leaky(hid[t]);
        o0 += lt * sW2[t * 3 + 0];
        o1 += lt * sW2[t * 3 + 1];
        o2 += lt * sW2[t * 3 + 2];
    }
    float* op = out + (size_t)n * 3;
    op[0] = o0; op[1] = o1; op[2] = o2;
}

// ---------------------------------------------------------------------------
extern "C" void kernel_launch(void* const* d_in, const int* in_sizes, int n_in,
                              void* d_out, int out_size, void* d_ws, size_t ws_size,
                              hipStream_t stream)
{
    const float* x      = (const float*)d_in[0];
    // d_in[1] = pos (unused by the reference)
    const int*   esrc   = (const int*)d_in[2];
    const int*   edst   = (const int*)d_in[3];
    const float* ew     = (const float*)d_in[4];
    const float* enc_W1 = (const float*)d_in[5];
    const float* enc_b1 = (const float*)d_in[6];
    const float* enc_W2 = (const float*)d_in[7];
    const float* enc_b2 = (const float*)d_in[8];
    const float* dec_W1 = (const float*)d_in[9];
    const float* dec_b1 = (const float*)d_in[10];
    const float* dec_W2 = (const float*)d_in[11];
    const float* dec_b2 = (const float*)d_in[12];
    const float* ln_g   = (const float*)d_in[13];
    const float* ln_b   = (const float*)d_in[14];
    const float* node_W = (const float*)d_in[15];
    const float* node_b = (const float*)d_in[16];
    const float* edge_W = (const float*)d_in[17];
    const float* edge_b = (const float*)d_in[18];
    const float* mlp_W  = (const float*)d_in[19];
    const float* mlp_b  = (const float*)d_in[20];

    // Workspace layout (fp32): H[N,64] | Y[N,32] | Z[N,32]  -> 51.2 MB
    float* H = (float*)d_ws;
    float* Y = H + (size_t)N_NODES * 64;
    float* Z = Y + (size_t)N_NODES * 32;

    const int nodeBlocks = (N_NODES + 255) / 256;
    const int edgeBlocks = (N_EDGES * 8 + 255) / 256;

    enc_kernel<<<nodeBlocks, 256, 0, stream>>>(x, enc_W1, enc_b1, enc_W2, enc_b2, H);

    for (int l = 0; l < LAYERS; l++) {
        layer_ln_gemm<<<nodeBlocks, 256, 0, stream>>>(
            H, Y, Z,
            ln_g + l * 64, ln_b + l * 64,
            node_W + l * 64 * 32, node_b + l * 32,
            edge_W + l * 64 * 32, edge_b + l * 32);
        scatter_kernel<<<edgeBlocks, 256, 0, stream>>>(esrc, edst, ew, Z, Y);
        mlp_kernel<<<nodeBlocks, 256, 0, stream>>>(Y, H, mlp_W + l * 32 * 64, mlp_b + l * 64);
    }

    dec_kernel<<<nodeBlocks, 256, 0, stream>>>(H, dec_W1, dec_b1, dec_W2, dec_b2, (float*)d_out);
}

// Round 2
// 687.337 us; speedup vs baseline: 3.4525x; 3.4525x over previous
//
#include <hip/hip_runtime.h>

#define N_NODES 100000
#define N_EDGES 1200000
#define LAYERS 4
#define SLOPE 0.01f

#define SCAN_ELEMS 1024                      // elems per scan1 block (256 thr x 4)
#define NB1 ((N_NODES + SCAN_ELEMS - 1) / SCAN_ELEMS)   // 98

__device__ __forceinline__ float leaky(float v) { return v >= 0.f ? v : SLOPE * v; }

// ---------------------------------------------------------------------------
// Encoder: h = leaky(x @ W1 + b1) @ W2 + b2     [N,16] -> [N,64]
// ---------------------------------------------------------------------------
__global__ __launch_bounds__(256) void enc_kernel(
    const float* __restrict__ x,
    const float* __restrict__ W1, const float* __restrict__ b1,
    const float* __restrict__ W2, const float* __restrict__ b2,
    float* __restrict__ H)
{
    __shared__ float sW1[128 * 16];   // [k][i] = W1[i][k]
    __shared__ float sW2[128 * 64];
    __shared__ float sb1[128];
    __shared__ float sb2[64];
    for (int idx = threadIdx.x; idx < 16 * 128; idx += 256) {
        int i = idx / 128, k = idx % 128;
        sW1[k * 16 + i] = W1[idx];
    }
    for (int idx = threadIdx.x; idx < 128 * 64; idx += 256) sW2[idx] = W2[idx];
    if (threadIdx.x < 128) sb1[threadIdx.x] = b1[threadIdx.x];
    if (threadIdx.x < 64)  sb2[threadIdx.x] = b2[threadIdx.x];
    __syncthreads();

    int n = blockIdx.x * 256 + threadIdx.x;
    if (n >= N_NODES) return;

    float xi[16];
    const float4* xv = (const float4*)(x + (size_t)n * 16);
    #pragma unroll
    for (int i = 0; i < 4; i++) {
        float4 t = xv[i];
        xi[4 * i] = t.x; xi[4 * i + 1] = t.y; xi[4 * i + 2] = t.z; xi[4 * i + 3] = t.w;
    }
    float acc[64];
    #pragma unroll
    for (int j = 0; j < 64; j++) acc[j] = sb2[j];

    for (int k = 0; k < 128; k++) {
        float t = sb1[k];
        const float4* w1r = (const float4*)(sW1 + k * 16);
        #pragma unroll
        for (int i = 0; i < 4; i++) {
            float4 w = w1r[i];
            t += xi[4 * i] * w.x + xi[4 * i + 1] * w.y + xi[4 * i + 2] * w.z + xi[4 * i + 3] * w.w;
        }
        t = leaky(t);
        const float4* w2r = (const float4*)(sW2 + k * 64);
        #pragma unroll
        for (int j = 0; j < 16; j++) {
            float4 w = w2r[j];
            acc[4 * j] += t * w.x; acc[4 * j + 1] += t * w.y;
            acc[4 * j + 2] += t * w.z; acc[4 * j + 3] += t * w.w;
        }
    }
    float4* out = (float4*)(H + (size_t)n * 64);
    #pragma unroll
    for (int j = 0; j < 16; j++)
        out[j] = make_float4(acc[4 * j], acc[4 * j + 1], acc[4 * j + 2], acc[4 * j + 3]);
}

// ---------------------------------------------------------------------------
// CSR build (counting sort by edge_dst) — runs once per launch
// ---------------------------------------------------------------------------
__global__ __launch_bounds__(256) void zero_counts(int* __restrict__ counts)
{
    int i = blockIdx.x * 256 + threadIdx.x;
    if (i < N_NODES) counts[i] = 0;
}

__global__ __launch_bounds__(256) void count_kernel(
    const int* __restrict__ dst, int* __restrict__ counts)
{
    int e = blockIdx.x * 256 + threadIdx.x;
    if (e < N_EDGES) atomicAdd(&counts[dst[e]], 1);
}

// scan1: per-block exclusive scan of counts (1024 elems/block), block sums out
__global__ __launch_bounds__(256) void scan1_kernel(
    const int* __restrict__ counts, int* __restrict__ offs, int* __restrict__ bsum)
{
    __shared__ int s[256];
    int b = blockIdx.x, t = threadIdx.x;
    int base = b * SCAN_ELEMS;
    int v[4]; int sum = 0;
    #pragma unroll
    for (int u = 0; u < 4; u++) {
        int idx = base + t * 4 + u;
        int c = (idx < N_NODES) ? counts[idx] : 0;
        v[u] = sum; sum += c;
    }
    s[t] = sum; __syncthreads();
    for (int off = 1; off < 256; off <<= 1) {
        int y = (t >= off) ? s[t - off] : 0;
        __syncthreads();
        s[t] += y;
        __syncthreads();
    }
    int excl = s[t] - sum;
    #pragma unroll
    for (int u = 0; u < 4; u++) {
        int idx = base + t * 4 + u;
        if (idx < N_NODES) offs[idx] = excl + v[u];
    }
    if (t == 255) bsum[b] = s[255];
}

// scan2: single block exclusive scan of NB1 block sums
__global__ __launch_bounds__(128) void scan2_kernel(
    const int* __restrict__ bsum, int* __restrict__ bscan)
{
    __shared__ int s[128];
    int t = threadIdx.x;
    int c = (t < NB1) ? bsum[t] : 0;
    s[t] = c; __syncthreads();
    for (int off = 1; off < 128; off <<= 1) {
        int y = (t >= off) ? s[t - off] : 0;
        __syncthreads();
        s[t] += y;
        __syncthreads();
    }
    if (t < NB1) bscan[t] = s[t] - c;
}

// scan3: add block offsets; duplicate into cursor; set sentinel
__global__ __launch_bounds__(256) void scan3_kernel(
    int* __restrict__ offs, int* __restrict__ cursor, const int* __restrict__ bscan)
{
    int b = blockIdx.x, t = threadIdx.x;
    int base = b * SCAN_ELEMS;
    int add = bscan[b];
    #pragma unroll
    for (int u = 0; u < 4; u++) {
        int idx = base + t * 4 + u;
        if (idx < N_NODES) {
            int v = offs[idx] + add;
            offs[idx] = v;
            cursor[idx] = v;
        }
    }
    if (b == 0 && t == 0) offs[N_NODES] = N_EDGES;
}

__global__ __launch_bounds__(256) void fill_kernel(
    const int* __restrict__ src, const int* __restrict__ dst,
    const float* __restrict__ w, int* __restrict__ cursor,
    int* __restrict__ ssrc, float* __restrict__ sw)
{
    int e = blockIdx.x * 256 + threadIdx.x;
    if (e >= N_EDGES) return;
    int d = dst[e];
    int p = atomicAdd(&cursor[d], 1);
    ssrc[p] = src[e];
    sw[p] = w[e];
}

// ---------------------------------------------------------------------------
// Per-layer: hn = LN(h)*g+b (in-place into H);
//   Y = hn @ node_W + node_b + edge_b
//   Z = hn @ edge_W                 (so msg@edge_W == sum_e w_e * Z[src])
// ---------------------------------------------------------------------------
__global__ __launch_bounds__(256) void layer_ln_gemm(
    float* H, float* __restrict__ Y, float* __restrict__ Z,
    const float* __restrict__ ln_g, const float* __restrict__ ln_b,
    const float* __restrict__ nodeW, const float* __restrict__ node_b,
    const float* __restrict__ edgeW, const float* __restrict__ edge_b)
{
    __shared__ float sNW[64 * 32];
    __shared__ float sEW[64 * 32];
    __shared__ float sg[64], sb[64], sby[32];
    for (int idx = threadIdx.x; idx < 64 * 32; idx += 256) {
        sNW[idx] = nodeW[idx];
        sEW[idx] = edgeW[idx];
    }
    if (threadIdx.x < 64) { sg[threadIdx.x] = ln_g[threadIdx.x]; sb[threadIdx.x] = ln_b[threadIdx.x]; }
    if (threadIdx.x < 32) { sby[threadIdx.x] = node_b[threadIdx.x] + edge_b[threadIdx.x]; }
    __syncthreads();

    int n = blockIdx.x * 256 + threadIdx.x;
    if (n >= N_NODES) return;

    const float4* hv = (const float4*)(H + (size_t)n * 64);
    float s = 0.f, s2 = 0.f;
    #pragma unroll
    for (int i = 0; i < 16; i++) {
        float4 t = hv[i];
        s  += t.x + t.y + t.z + t.w;
        s2 += t.x * t.x + t.y * t.y + t.z * t.z + t.w * t.w;
    }
    float mu  = s * (1.f / 64.f);
    float var = s2 * (1.f / 64.f) - mu * mu;
    float rs  = rsqrtf(var + 1e-5f);

    float accY[32], accZ[32];
    #pragma unroll
    for (int j = 0; j < 32; j++) { accY[j] = sby[j]; accZ[j] = 0.f; }

    float4* hnv = (float4*)(H + (size_t)n * 64);
    for (int kc = 0; kc < 16; kc++) {
        float4 hc = hv[kc];
        float hn4[4];
        #pragma unroll
        for (int u = 0; u < 4; u++) {
            int k = kc * 4 + u;
            float hval = (u == 0) ? hc.x : (u == 1) ? hc.y : (u == 2) ? hc.z : hc.w;
            float hnk = (hval - mu) * rs * sg[k] + sb[k];
            hn4[u] = hnk;
            const float4* nwr = (const float4*)(sNW + k * 32);
            const float4* ewr = (const float4*)(sEW + k * 32);
            #pragma unroll
            for (int j = 0; j < 8; j++) {
                float4 wn = nwr[j];
                float4 we = ewr[j];
                accY[4 * j]     += hnk * wn.x; accY[4 * j + 1] += hnk * wn.y;
                accY[4 * j + 2] += hnk * wn.z; accY[4 * j + 3] += hnk * wn.w;
                accZ[4 * j]     += hnk * we.x; accZ[4 * j + 1] += hnk * we.y;
                accZ[4 * j + 2] += hnk * we.z; accZ[4 * j + 3] += hnk * we.w;
            }
        }
        hnv[kc] = make_float4(hn4[0], hn4[1], hn4[2], hn4[3]);
    }
    float4* yv = (float4*)(Y + (size_t)n * 32);
    float4* zv = (float4*)(Z + (size_t)n * 32);
    #pragma unroll
    for (int j = 0; j < 8; j++) {
        yv[j] = make_float4(accY[4 * j], accY[4 * j + 1], accY[4 * j + 2], accY[4 * j + 3]);
        zv[j] = make_float4(accZ[4 * j], accZ[4 * j + 1], accZ[4 * j + 2], accZ[4 * j + 3]);
    }
}

// ---------------------------------------------------------------------------
// Gather: Y[n] += sum over incoming edges of w_e * Z[src_e]
// 8 lanes per node; each lane owns one float4 column slice (lanes read
// consecutive float4s of a Z row -> 128B coalesced per edge).
// ---------------------------------------------------------------------------
__global__ __launch_bounds__(256) void gather_kernel(
    const int* __restrict__ offs, const int* __restrict__ ssrc,
    const float* __restrict__ sw,
    const float* __restrict__ Z, float* __restrict__ Y)
{
    int gid = blockIdx.x * 256 + threadIdx.x;
    int node = gid >> 3;
    int lane = gid & 7;
    if (node >= N_NODES) return;
    int p0 = offs[node], p1 = offs[node + 1];
    float4 acc = make_float4(0.f, 0.f, 0.f, 0.f);
    for (int p = p0; p < p1; p++) {
        int s = ssrc[p];
        float we = sw[p];
        float4 zv = ((const float4*)Z)[(size_t)s * 8 + lane];
        acc.x += we * zv.x; acc.y += we * zv.y;
        acc.z += we * zv.z; acc.w += we * zv.w;
    }
    float4* yp = (float4*)(Y + (size_t)node * 32) + lane;
    float4 y = *yp;
    y.x += acc.x; y.y += acc.y; y.z += acc.z; y.w += acc.w;
    *yp = y;
}

// ---------------------------------------------------------------------------
// MLP + residual: h = leaky(Y) @ mlp_W + mlp_b + hn
// ---------------------------------------------------------------------------
__global__ __launch_bounds__(256) void mlp_kernel(
    const float* __restrict__ Y, float* H,
    const float* __restrict__ mlpW, const float* __restrict__ mlp_b)
{
    __shared__ float sW[32 * 64];
    __shared__ float sb2[64];
    for (int idx = threadIdx.x; idx < 32 * 64; idx += 256) sW[idx] = mlpW[idx];
    if (threadIdx.x < 64) sb2[threadIdx.x] = mlp_b[threadIdx.x];
    __syncthreads();

    int n = blockIdx.x * 256 + threadIdx.x;
    if (n >= N_NODES) return;

    float ly[32];
    const float4* yv = (const float4*)(Y + (size_t)n * 32);
    #pragma unroll
    for (int i = 0; i < 8; i++) {
        float4 t = yv[i];
        ly[4 * i] = leaky(t.x); ly[4 * i + 1] = leaky(t.y);
        ly[4 * i + 2] = leaky(t.z); ly[4 * i + 3] = leaky(t.w);
    }
    float acc[64];
    #pragma unroll
    for (int j = 0; j < 64; j++) acc[j] = sb2[j];
    for (int k = 0; k < 32; k++) {
        float t = ly[k];
        const float4* wr = (const float4*)(sW + k * 64);
        #pragma unroll
        for (int j = 0; j < 16; j++) {
            float4 wv = wr[j];
            acc[4 * j] += t * wv.x; acc[4 * j + 1] += t * wv.y;
            acc[4 * j + 2] += t * wv.z; acc[4 * j + 3] += t * wv.w;
        }
    }
    float4* hp = (float4*)(H + (size_t)n * 64);
    #pragma unroll
    for (int j = 0; j < 16; j++) {
        float4 hn = hp[j];
        hp[j] = make_float4(acc[4 * j] + hn.x, acc[4 * j + 1] + hn.y,
                            acc[4 * j + 2] + hn.z, acc[4 * j + 3] + hn.w);
    }
}

// ---------------------------------------------------------------------------
// Decoder: out = leaky(h @ W1 + b1) @ W2 + b2     [N,64] -> [N,3]
// ---------------------------------------------------------------------------
__global__ __launch_bounds__(256) void dec_kernel(
    const float* __restrict__ H,
    const float* __restrict__ W1, const float* __restrict__ b1,
    const float* __restrict__ W2, const float* __restrict__ b2,
    float* __restrict__ out)
{
    __shared__ float sW1t[24 * 64];   // [t][k] = W1[k][t]
    __shared__ float sb1[24];
    __shared__ float sW2[24 * 3];
    __shared__ float sb2v[3];
    for (int idx = threadIdx.x; idx < 64 * 24; idx += 256) {
        int k = idx / 24, t = idx % 24;
        sW1t[t * 64 + k] = W1[idx];
    }
    if (threadIdx.x < 24) sb1[threadIdx.x] = b1[threadIdx.x];
    if (threadIdx.x < 72) sW2[threadIdx.x] = W2[threadIdx.x];
    if (threadIdx.x < 3)  sb2v[threadIdx.x] = b2[threadIdx.x];
    __syncthreads();

    int n = blockIdx.x * 256 + threadIdx.x;
    if (n >= N_NODES) return;

    float hid[24];
    #pragma unroll
    for (int t = 0; t < 24; t++) hid[t] = sb1[t];

    const float4* hv = (const float4*)(H + (size_t)n * 64);
    for (int i = 0; i < 16; i++) {
        float4 hc = hv[i];
        #pragma unroll
        for (int t = 0; t < 24; t++) {
            float4 wv = *(const float4*)(sW1t + t * 64 + 4 * i);
            hid[t] += hc.x * wv.x + hc.y * wv.y + hc.z * wv.z + hc.w * wv.w;
        }
    }
    float o0 = sb2v[0], o1 = sb2v[1], o2 = sb2v[2];
    #pragma unroll
    for (int t = 0; t < 24; t++) {
        float lt = leaky(hid[t]);
        o0 += lt * sW2[t * 3 + 0];
        o1 += lt * sW2[t * 3 + 1];
        o2 += lt * sW2[t * 3 + 2];
    }
    float* op = out + (size_t)n * 3;
    op[0] = o0; op[1] = o1; op[2] = o2;
}

// ---------------------------------------------------------------------------
extern "C" void kernel_launch(void* const* d_in, const int* in_sizes, int n_in,
                              void* d_out, int out_size, void* d_ws, size_t ws_size,
                              hipStream_t stream)
{
    const float* x      = (const float*)d_in[0];
    const int*   esrc   = (const int*)d_in[2];
    const int*   edst   = (const int*)d_in[3];
    const float* ew     = (const float*)d_in[4];
    const float* enc_W1 = (const float*)d_in[5];
    const float* enc_b1 = (const float*)d_in[6];
    const float* enc_W2 = (const float*)d_in[7];
    const float* enc_b2 = (const float*)d_in[8];
    const float* dec_W1 = (const float*)d_in[9];
    const float* dec_b1 = (const float*)d_in[10];
    const float* dec_W2 = (const float*)d_in[11];
    const float* dec_b2 = (const float*)d_in[12];
    const float* ln_g   = (const float*)d_in[13];
    const float* ln_b   = (const float*)d_in[14];
    const float* node_W = (const float*)d_in[15];
    const float* node_b = (const float*)d_in[16];
    const float* edge_W = (const float*)d_in[17];
    const float* edge_b = (const float*)d_in[18];
    const float* mlp_W  = (const float*)d_in[19];
    const float* mlp_b  = (const float*)d_in[20];

    // Workspace layout:
    // floats: H[N*64] | Y[N*32] | Z[N*32] | sw[E]
    // ints:   counts[N] | offs[N+1] | cursor[N] | ssrc[E] | bsum[NB1] | bscan[NB1]
    float* H  = (float*)d_ws;
    float* Y  = H + (size_t)N_NODES * 64;
    float* Z  = Y + (size_t)N_NODES * 32;
    float* sw = Z + (size_t)N_NODES * 32;
    int* counts = (int*)(sw + N_EDGES);
    int* offs   = counts + N_NODES;          // N_NODES+1 entries
    int* cursor = offs + N_NODES + 1;
    int* ssrc   = cursor + N_NODES;
    int* bsum   = ssrc + N_EDGES;
    int* bscan  = bsum + NB1;

    const int nodeBlocks  = (N_NODES + 255) / 256;
    const int edgeBlocks  = (N_EDGES + 255) / 256;
    const int gatherBlocks = (N_NODES * 8 + 255) / 256;

    // --- CSR build (counting sort by dst) ---
    zero_counts<<<nodeBlocks, 256, 0, stream>>>(counts);
    count_kernel<<<edgeBlocks, 256, 0, stream>>>(edst, counts);
    scan1_kernel<<<NB1, 256, 0, stream>>>(counts, offs, bsum);
    scan2_kernel<<<1, 128, 0, stream>>>(bsum, bscan);
    scan3_kernel<<<NB1, 256, 0, stream>>>(offs, cursor, bscan);
    fill_kernel<<<edgeBlocks, 256, 0, stream>>>(esrc, edst, ew, cursor, ssrc, sw);

    // --- network ---
    enc_kernel<<<nodeBlocks, 256, 0, stream>>>(x, enc_W1, enc_b1, enc_W2, enc_b2, H);

    for (int l = 0; l < LAYERS; l++) {
        layer_ln_gemm<<<nodeBlocks, 256, 0, stream>>>(
            H, Y, Z,
            ln_g + l * 64, ln_b + l * 64,
            node_W + l * 64 * 32, node_b + l * 32,
            edge_W + l * 64 * 32, edge_b + l * 32);
        gather_kernel<<<gatherBlocks, 256, 0, stream>>>(offs, ssrc, sw, Z, Y);
        mlp_kernel<<<nodeBlocks, 256, 0, stream>>>(Y, H, mlp_W + l * 32 * 64, mlp_b + l * 64);
    }

    dec_kernel<<<nodeBlocks, 256, 0, stream>>>(H, dec_W1, dec_b1, dec_W2, dec_b2, (float*)d_out);
}